// Round 2
// baseline (1498.348 us; speedup 1.0000x reference)
//
#include <hip/hip_runtime.h>
#include <cstdint>
#include <cstddef>

#define TSTEPS 1000
#define NB     256
#define NR     200
#define NI     10
#define ALPHA_F     0.1f
#define NOISE_STD_F 0.01f

// ---------------- JAX threefry2x32-20, key = (0, 42) --------------------
// Partitionable variant: element j uses counter (hi=0, lo=j); draw = x0^x1.
__device__ __forceinline__ uint32_t rotl32(uint32_t v, uint32_t d) {
  return (v << d) | (v >> (32u - d));
}

__device__ __forceinline__ uint32_t threefry_bits(uint32_t c1) {
  const uint32_t ks0 = 0u;
  const uint32_t ks1 = 42u;
  const uint32_t ks2 = 0x1BD11BDAu ^ ks0 ^ ks1;
  uint32_t x0 = ks0;
  uint32_t x1 = c1 + ks1;
#define TFR(r) { x0 += x1; x1 = rotl32(x1, (r)); x1 ^= x0; }
  TFR(13) TFR(15) TFR(26) TFR(6)   x0 += ks1; x1 += ks2 + 1u;
  TFR(17) TFR(29) TFR(16) TFR(24)  x0 += ks2; x1 += ks0 + 2u;
  TFR(13) TFR(15) TFR(26) TFR(6)   x0 += ks0; x1 += ks1 + 3u;
  TFR(17) TFR(29) TFR(16) TFR(24)  x0 += ks1; x1 += ks2 + 4u;
  TFR(13) TFR(15) TFR(26) TFR(6)   x0 += ks2; x1 += ks0 + 5u;
#undef TFR
  return x0 ^ x1;
}

// XLA ErfInv32 (Giles). log1p(-x^2) -> __logf(fma(-x,x,1)): |u|<=1-2^-24
// keeps the argument >= 2^-23, tail error << threshold.
__device__ __forceinline__ float erfinv_f32(float x) {
  float w = -__logf(fmaf(-x, x, 1.0f));
  float p;
  if (w < 5.0f) {
    w = w - 2.5f;
    p = 2.81022636e-08f;
    p = fmaf(p, w, 3.43273939e-07f);
    p = fmaf(p, w, -3.5233877e-06f);
    p = fmaf(p, w, -4.39150654e-06f);
    p = fmaf(p, w, 0.00021858087f);
    p = fmaf(p, w, -0.00125372503f);
    p = fmaf(p, w, -0.00417768164f);
    p = fmaf(p, w, 0.246640727f);
    p = fmaf(p, w, 1.50140941f);
  } else {
    w = sqrtf(w) - 3.0f;
    p = -0.000200214257f;
    p = fmaf(p, w, 0.000100950558f);
    p = fmaf(p, w, 0.00134934322f);
    p = fmaf(p, w, -0.00367342844f);
    p = fmaf(p, w, 0.00573950773f);
    p = fmaf(p, w, -0.0076224613f);
    p = fmaf(p, w, 0.00943887047f);
    p = fmaf(p, w, 1.00167406f);
    p = fmaf(p, w, 2.83297682f);
  }
  return p * x;
}

__device__ __forceinline__ float jax_normal(uint32_t idx) {
  uint32_t bits = threefry_bits(idx);
  float f = __uint_as_float((bits >> 9) | 0x3F800000u) - 1.0f;  // [0,1)
  const float lo = -0.99999994f;                                 // nextafter(-1,0)
  float u = fmaf(f, 2.0f, lo);
  u = fmaxf(lo, u);
  return 1.41421356f * erfinv_f32(u);
}

// exp-based tanh: ~2ulp, no ocml branches. tanh(y)=sign(y)*(1-t)/(1+t),
// t=exp(-2|y|).
__device__ __forceinline__ float tanh_fast(float y) {
  float ay = fabsf(y);
  float t  = __expf(-2.0f * ay);
  float r  = (1.0f - t) * __frcp_rn(1.0f + t);
  return copysignf(r, y);
}

// LDS-only barrier: orders DS ops without draining vmcnt (keeps the per-step
// global `out` stores and the x-pipeline loads in flight — __syncthreads
// would wait vmcnt(0)).
__device__ __forceinline__ void wg_barrier_lds() {
  asm volatile("s_waitcnt lgkmcnt(0)\n\ts_barrier" ::: "memory");
}

// ---------------- fully-fused step: ONE barrier, no reduction ------------
// 256 threads = 4 waves, 50 rows per wave (lane<50). Each row-lane:
//   - computes its OWN eta(t+1) via Threefry (issued FIRST: the ~280-cycle
//     serial chain hides under the 400-cycle FMA issue stream; eta lives in
//     a register double-buffer, no LDS)
//   - full 200-wide dot product from broadcast ds_read_b128 of sh_h[CUR],
//     in the SAME 10x20 chunk order as the previous kernel (bit-identical)
//   - tanh + Euler update, write sh_h[NXT] (double-buffered: removes the
//     read/write WAR barrier) + global out
// tid 50..59 (wave 0 idle lanes): x double-buffer pipeline, 2-step slack.
template <int CUR, bool PF>
__device__ __forceinline__ void rnn_step(
    int t, int row, bool row_active, bool xpipe, int jx,
    const float (&w)[NR], const float (&winp)[NI], float brec_r,
    float& h_reg, float& eta_use, float& eta_fill,
    float& xnA, float& xnB, float*& obp,
    const float* __restrict__ xb, uint32_t nbase,
    float (&sh_h)[2][NR], float (&sh_x)[2][16]) {
  constexpr int NXT = CUR ^ 1;

  if (row_active) {
    // ---- noise for step t+1, issued early (independent of h) ----
    if (PF) {
      uint32_t idx = (uint32_t)(t + 1) * (uint32_t)(NB * NR) + nbase;
      eta_fill = NOISE_STD_F * jax_normal(idx);
    }

    // ---- recurrent drive: y = brec + sum of 10 ordered 20-chunks ----
    float y = brec_r;
    const float* hb = &sh_h[CUR][0];
#pragma unroll
    for (int q = 0; q < 10; ++q) {
      float4 h0 = *(const float4*)(hb + 20 * q + 0);
      float4 h1 = *(const float4*)(hb + 20 * q + 4);
      float4 h2 = *(const float4*)(hb + 20 * q + 8);
      float4 h3 = *(const float4*)(hb + 20 * q + 12);
      float4 h4 = *(const float4*)(hb + 20 * q + 16);
      float p = 0.0f;
      p = fmaf(w[20 * q +  0], h0.x, p);
      p = fmaf(w[20 * q +  1], h0.y, p);
      p = fmaf(w[20 * q +  2], h0.z, p);
      p = fmaf(w[20 * q +  3], h0.w, p);
      p = fmaf(w[20 * q +  4], h1.x, p);
      p = fmaf(w[20 * q +  5], h1.y, p);
      p = fmaf(w[20 * q +  6], h1.z, p);
      p = fmaf(w[20 * q +  7], h1.w, p);
      p = fmaf(w[20 * q +  8], h2.x, p);
      p = fmaf(w[20 * q +  9], h2.y, p);
      p = fmaf(w[20 * q + 10], h2.z, p);
      p = fmaf(w[20 * q + 11], h2.w, p);
      p = fmaf(w[20 * q + 12], h3.x, p);
      p = fmaf(w[20 * q + 13], h3.y, p);
      p = fmaf(w[20 * q + 14], h3.z, p);
      p = fmaf(w[20 * q + 15], h3.w, p);
      p = fmaf(w[20 * q + 16], h4.x, p);
      p = fmaf(w[20 * q + 17], h4.y, p);
      p = fmaf(w[20 * q + 18], h4.z, p);
      p = fmaf(w[20 * q + 19], h4.w, p);
      y += p;
    }

    // ---- input drive (same fma order as before) ----
    float4 xv0 = *(const float4*)(&sh_x[CUR][0]);
    float4 xv1 = *(const float4*)(&sh_x[CUR][4]);
    float2 xv2 = *(const float2*)(&sh_x[CUR][8]);
    y = fmaf(winp[0], xv0.x, y);
    y = fmaf(winp[1], xv0.y, y);
    y = fmaf(winp[2], xv0.z, y);
    y = fmaf(winp[3], xv0.w, y);
    y = fmaf(winp[4], xv1.x, y);
    y = fmaf(winp[5], xv1.y, y);
    y = fmaf(winp[6], xv1.z, y);
    y = fmaf(winp[7], xv1.w, y);
    y = fmaf(winp[8], xv2.x, y);
    y = fmaf(winp[9], xv2.y, y);

    float rate = tanh_fast(y);
    float hn = h_reg + ALPHA_F * (((-h_reg) + rate) + eta_use);
    h_reg = hn;
    sh_h[NXT][row] = hn;
    *obp = hn;
    obp += NR;
  } else if (xpipe) {
    if (PF) {
      // write x(t+1), in flight for 2 steps -> no HBM stall here
      sh_x[NXT][jx] = (CUR == 0) ? xnA : xnB;
      int tf = t + 3;
      if (tf > TSTEPS - 1) tf = TSTEPS - 1;   // harmless redundant tail load
      float xl = xb[tf * NI + jx];
      if (CUR == 0) xnA = xl; else xnB = xl;
    }
  }
  wg_barrier_lds();
}

// ---------------- persistent RNN kernel: 1 workgroup per batch ----------
// 256 threads = 4 waves = 1 wave/SIMD. Occupancy is intentionally low:
// all latency hiding is ILP within the fused step.
__launch_bounds__(256, 1)
__global__ void rnn_persistent(const float* __restrict__ x,
                               const float* __restrict__ h0,
                               const float* __restrict__ Winp,
                               const float* __restrict__ Wrec,
                               const float* __restrict__ brec,
                               float* __restrict__ out) {
  const int b   = blockIdx.x;
  const int tid = threadIdx.x;
  const int wv  = tid >> 6;
  const int ln  = tid & 63;

  __shared__ float sh_h[2][NR];   // double-buffered hidden state
  __shared__ float sh_x[2][16];   // x_t double buffer

  const bool row_active = (ln < 50);
  const int  row        = wv * 50 + ln;        // valid iff row_active
  const bool xpipe      = (tid >= 50 && tid < 50 + NI);
  const int  jx         = tid - 50;

  const float* xb = x + (size_t)b * TSTEPS * NI;
  float* ob       = out + (size_t)b * TSTEPS * NR;

  // --- stationary full W_rec row in registers (~200 VGPR, 1 wave/SIMD) ---
  float w[NR];
  float winp[NI];
  float brec_r = 0.0f;
  float h_reg  = 0.0f;
  float etaA = 0.0f, etaB = 0.0f;
  float* obp = nullptr;
  uint32_t nbase = 0;

  if (row_active) {
    const float* wr = Wrec + (size_t)row * NR;
#pragma unroll
    for (int i = 0; i < 50; ++i) {
      float4 v = *(const float4*)(wr + 4 * i);
      w[4 * i + 0] = v.x; w[4 * i + 1] = v.y;
      w[4 * i + 2] = v.z; w[4 * i + 3] = v.w;
    }
#pragma unroll
    for (int i = 0; i < NI; ++i) winp[i] = Winp[row * NI + i];
    brec_r = brec[row];
    h_reg  = h0[(size_t)b * NR + row];
    sh_h[0][row] = h_reg;
    obp = ob + row;
    nbase = (uint32_t)b * (uint32_t)NR + (uint32_t)row;
    etaA = NOISE_STD_F * jax_normal(nbase);              // eta(0)
  } else if (xpipe) {
    sh_x[0][jx] = xb[jx];          // x(0)
    etaA = xb[NI + jx];            // (reuse: not used; keep regs simple)
    xnA_init:;
  }
  float xnA = 0.0f, xnB = 0.0f;
  if (xpipe) {
    xnA = xb[NI + jx];             // x(1), consumed at t=0
    xnB = xb[2 * NI + jx];         // x(2), consumed at t=1
  }
  __syncthreads();

  // main loop: unroll x2 for compile-time buffer/eta indices; tail peeled
  for (int t = 0; t < TSTEPS - 2; t += 2) {
    rnn_step<0, true>(t,     row, row_active, xpipe, jx, w, winp, brec_r,
                      h_reg, etaA, etaB, xnA, xnB, obp, xb, nbase, sh_h, sh_x);
    rnn_step<1, true>(t + 1, row, row_active, xpipe, jx, w, winp, brec_r,
                      h_reg, etaB, etaA, xnA, xnB, obp, xb, nbase, sh_h, sh_x);
  }
  rnn_step<0, true >(TSTEPS - 2, row, row_active, xpipe, jx, w, winp, brec_r,
                     h_reg, etaA, etaB, xnA, xnB, obp, xb, nbase, sh_h, sh_x);
  rnn_step<1, false>(TSTEPS - 1, row, row_active, xpipe, jx, w, winp, brec_r,
                     h_reg, etaB, etaA, xnA, xnB, obp, xb, nbase, sh_h, sh_x);
}

extern "C" void kernel_launch(void* const* d_in, const int* in_sizes, int n_in,
                              void* d_out, int out_size, void* d_ws, size_t ws_size,
                              hipStream_t stream) {
  const float* x    = (const float*)d_in[0];  // [256,1000,10]
  const float* h0   = (const float*)d_in[1];  // [256,200]
  const float* Winp = (const float*)d_in[2];  // [200,10]
  const float* Wrec = (const float*)d_in[3];  // [200,200]
  const float* brec = (const float*)d_in[4];  // [200]
  float* out = (float*)d_out;                 // [256,1000,200]
  (void)in_sizes; (void)n_in; (void)out_size; (void)d_ws; (void)ws_size;

  rnn_persistent<<<dim3(NB), dim3(256), 0, stream>>>(x, h0, Winp, Wrec, brec, out);
}

// Round 3
// 885.693 us; speedup vs baseline: 1.6917x; 1.6917x over previous
//
#include <hip/hip_runtime.h>
#include <cstdint>
#include <cstddef>

#define TSTEPS 1000
#define NB     256
#define NR     200
#define NI     10
#define ALPHA_F     0.1f
#define NOISE_STD_F 0.01f
#define ETA_STRIDE  (NB * NR)          // 51200 floats per timestep
#define ETA_FLOATS  ((size_t)TSTEPS * NB * NR)

// ---------------- JAX threefry2x32-20, key = (0, 42) --------------------
// Partitionable variant: element j uses counter (hi=0, lo=j); draw = x0^x1.
__device__ __forceinline__ uint32_t rotl32(uint32_t v, uint32_t d) {
  return (v << d) | (v >> (32u - d));
}

__device__ __forceinline__ uint32_t threefry_bits(uint32_t c1) {
  const uint32_t ks0 = 0u;
  const uint32_t ks1 = 42u;
  const uint32_t ks2 = 0x1BD11BDAu ^ ks0 ^ ks1;
  uint32_t x0 = ks0;
  uint32_t x1 = c1 + ks1;
#define TFR(r) { x0 += x1; x1 = rotl32(x1, (r)); x1 ^= x0; }
  TFR(13) TFR(15) TFR(26) TFR(6)   x0 += ks1; x1 += ks2 + 1u;
  TFR(17) TFR(29) TFR(16) TFR(24)  x0 += ks2; x1 += ks0 + 2u;
  TFR(13) TFR(15) TFR(26) TFR(6)   x0 += ks0; x1 += ks1 + 3u;
  TFR(17) TFR(29) TFR(16) TFR(24)  x0 += ks1; x1 += ks2 + 4u;
  TFR(13) TFR(15) TFR(26) TFR(6)   x0 += ks2; x1 += ks0 + 5u;
#undef TFR
  return x0 ^ x1;
}

// XLA ErfInv32 (Giles). log1p(-x^2) -> __logf(fma(-x,x,1)): |u|<=1-2^-24
// keeps the argument >= 2^-23, tail error << threshold.
__device__ __forceinline__ float erfinv_f32(float x) {
  float w = -__logf(fmaf(-x, x, 1.0f));
  float p;
  if (w < 5.0f) {
    w = w - 2.5f;
    p = 2.81022636e-08f;
    p = fmaf(p, w, 3.43273939e-07f);
    p = fmaf(p, w, -3.5233877e-06f);
    p = fmaf(p, w, -4.39150654e-06f);
    p = fmaf(p, w, 0.00021858087f);
    p = fmaf(p, w, -0.00125372503f);
    p = fmaf(p, w, -0.00417768164f);
    p = fmaf(p, w, 0.246640727f);
    p = fmaf(p, w, 1.50140941f);
  } else {
    w = sqrtf(w) - 3.0f;
    p = -0.000200214257f;
    p = fmaf(p, w, 0.000100950558f);
    p = fmaf(p, w, 0.00134934322f);
    p = fmaf(p, w, -0.00367342844f);
    p = fmaf(p, w, 0.00573950773f);
    p = fmaf(p, w, -0.0076224613f);
    p = fmaf(p, w, 0.00943887047f);
    p = fmaf(p, w, 1.00167406f);
    p = fmaf(p, w, 2.83297682f);
  }
  return p * x;
}

__device__ __forceinline__ float jax_normal(uint32_t idx) {
  uint32_t bits = threefry_bits(idx);
  float f = __uint_as_float((bits >> 9) | 0x3F800000u) - 1.0f;  // [0,1)
  const float lo = -0.99999994f;                                 // nextafter(-1,0)
  float u = fmaf(f, 2.0f, lo);
  u = fmaxf(lo, u);
  return 1.41421356f * erfinv_f32(u);
}

// exp-based tanh: ~2ulp, no ocml branches. tanh(y)=sign(y)*(1-t)/(1+t),
// t=exp(-2|y|).
__device__ __forceinline__ float tanh_fast(float y) {
  float ay = fabsf(y);
  float t  = __expf(-2.0f * ay);
  float r  = (1.0f - t) * __frcp_rn(1.0f + t);
  return copysignf(r, y);
}

// LDS-only barrier: orders DS ops without draining vmcnt (keeps the per-step
// global `out` stores and the eta/x pipeline loads in flight — __syncthreads
// would wait vmcnt(0)).
__device__ __forceinline__ void wg_barrier_lds() {
  asm volatile("s_waitcnt lgkmcnt(0)\n\ts_barrier" ::: "memory");
}

// ---------------- dense noise pre-generation (map kernel) ----------------
// ws[i] = NOISE_STD * normal(threefry(i)) for i in [0, T*B*NR).
// Pure VALU map at full occupancy: ~62 us floor on 256 CUs.
__launch_bounds__(256)
__global__ void noise_fill(float* __restrict__ ws) {
  const int64_t nq = (int64_t)ETA_FLOATS / 4;          // float4 groups
  const int64_t stride = (int64_t)gridDim.x * blockDim.x;
  for (int64_t i = (int64_t)blockIdx.x * blockDim.x + threadIdx.x;
       i < nq; i += stride) {
    uint32_t base = (uint32_t)(i * 4);
    float4 v;
    v.x = NOISE_STD_F * jax_normal(base + 0u);
    v.y = NOISE_STD_F * jax_normal(base + 1u);
    v.z = NOISE_STD_F * jax_normal(base + 2u);
    v.w = NOISE_STD_F * jax_normal(base + 3u);
    ((float4*)ws)[i] = v;
  }
}

// ---------------- one RNN step, compile-time double-buffer index ---------
// CUR: which eta/x buffer this step consumes (t&1). PF: prefetch for the
// next step (false only for the final step). PRE: eta comes from global
// workspace via a 2-step register pipeline (noise pre-generated); else
// eta is computed in-kernel (fallback, identical to the 898us R1 kernel).
// Phase A (tid<500): r=tid%50 owns rows 4r..4r+3, k=tid/50 owns k-chunk
//                    [20k,20k+20); partial -> LDS k-major (1 b128/thread).
// Phase B: tid<200                update (reduce+input+tanh+state+store)
//   PRE : tid 256..305            eta pipeline: ds_write arrived eta(t+1);
//                                 issue float4 load eta(t+3) (2-step slack)
//   !PRE: tid 256..447 & 200..207 one Threefry value each for eta(t+1)
//   both: tid 448..457            x pipeline (2-step slack)
template <int CUR, bool PF, bool PRE>
__device__ __forceinline__ void rnn_step(
    int t, int tid, bool mac_active,
    const float (&w)[4][20], const float (&winp)[NI], float brec_r,
    float& h_reg, float*& obp, float& xnA, float& xnB,
    float4& enA, float4& enB,
    const float* __restrict__ xb, const float* __restrict__ etab,
    uint32_t nb_b,
    const float* __restrict__ hp, float* __restrict__ part_wp,
    float* __restrict__ sh_h, float* __restrict__ sh_part,
    float (*__restrict__ sh_x)[16], float (*__restrict__ sh_eta)[NR]) {
  constexpr int NXT = CUR ^ 1;

  // ---------- phase A: MACs from sh_h ----------
  if (mac_active) {
    float a0 = 0.0f, a1 = 0.0f, a2 = 0.0f, a3 = 0.0f;
#pragma unroll
    for (int q = 0; q < 5; ++q) {
      float4 hv = *(const float4*)(hp + 4 * q);
      a0 = fmaf(w[0][4 * q + 0], hv.x, a0);
      a1 = fmaf(w[1][4 * q + 0], hv.x, a1);
      a2 = fmaf(w[2][4 * q + 0], hv.x, a2);
      a3 = fmaf(w[3][4 * q + 0], hv.x, a3);
      a0 = fmaf(w[0][4 * q + 1], hv.y, a0);
      a1 = fmaf(w[1][4 * q + 1], hv.y, a1);
      a2 = fmaf(w[2][4 * q + 1], hv.y, a2);
      a3 = fmaf(w[3][4 * q + 1], hv.y, a3);
      a0 = fmaf(w[0][4 * q + 2], hv.z, a0);
      a1 = fmaf(w[1][4 * q + 2], hv.z, a1);
      a2 = fmaf(w[2][4 * q + 2], hv.z, a2);
      a3 = fmaf(w[3][4 * q + 2], hv.z, a3);
      a0 = fmaf(w[0][4 * q + 3], hv.w, a0);
      a1 = fmaf(w[1][4 * q + 3], hv.w, a1);
      a2 = fmaf(w[2][4 * q + 3], hv.w, a2);
      a3 = fmaf(w[3][4 * q + 3], hv.w, a3);
    }
    // k-major float4 write: conflict-free, 16B aligned (200%4==0)
    *(float4*)part_wp = make_float4(a0, a1, a2, a3);
  }
  wg_barrier_lds();

  // ---------- phase B ----------
  if (tid < NR) {
    float y = brec_r;
#pragma unroll
    for (int q = 0; q < 10; ++q) y += sh_part[q * NR + tid];
    // vectorized broadcast reads of x_t (same fma order as before)
    float4 xv0 = *(const float4*)(&sh_x[CUR][0]);
    float4 xv1 = *(const float4*)(&sh_x[CUR][4]);
    float2 xv2 = *(const float2*)(&sh_x[CUR][8]);
    y = fmaf(winp[0], xv0.x, y);
    y = fmaf(winp[1], xv0.y, y);
    y = fmaf(winp[2], xv0.z, y);
    y = fmaf(winp[3], xv0.w, y);
    y = fmaf(winp[4], xv1.x, y);
    y = fmaf(winp[5], xv1.y, y);
    y = fmaf(winp[6], xv1.z, y);
    y = fmaf(winp[7], xv1.w, y);
    y = fmaf(winp[8], xv2.x, y);
    y = fmaf(winp[9], xv2.y, y);
    float rate = tanh_fast(y);
    float eta  = sh_eta[CUR][tid];
    float hn = h_reg + ALPHA_F * (((-h_reg) + rate) + eta);
    h_reg = hn;
    sh_h[tid] = hn;
    *obp = hn;
    obp += NR;
  } else if (PRE ? (tid >= 256 && tid < 256 + NR / 4)
                 : ((tid >= 256 && tid < 448) || (tid < 208))) {
    if (PF) {
      if constexpr (PRE) {
        // eta pipeline: write eta(t+1) (in flight 2 steps), load eta(t+3)
        int j = tid - 256;
        *(float4*)(&sh_eta[NXT][4 * j]) = (CUR == 0) ? enA : enB;
        int tf = t + 3;
        if (tf > TSTEPS - 1) tf = TSTEPS - 1;  // harmless redundant tail load
        float4 e = *(const float4*)(etab + (size_t)tf * ETA_STRIDE + 4 * j);
        if (CUR == 0) enA = e; else enB = e;
      } else {
        // 200 noise threads, exactly one Threefry value each
        int n = (tid >= 256) ? (tid - 256) : (tid - 8);  // 0..191 / 192..199
        uint32_t idx = (uint32_t)(t + 1) * (uint32_t)(NB * NR) + nb_b + (uint32_t)n;
        sh_eta[NXT][n] = NOISE_STD_F * jax_normal(idx);
      }
    }
  } else if (tid >= 448 && tid < 448 + NI) {
    if (PF) {
      // write x(t+1), in flight for 2 steps -> no HBM stall here
      int j = tid - 448;
      sh_x[NXT][j] = (CUR == 0) ? xnA : xnB;
      int tf = t + 3;
      if (tf > TSTEPS - 1) tf = TSTEPS - 1;
      float xl = xb[tf * NI + j];
      if (CUR == 0) xnA = xl; else xnB = xl;
    }
  }
  wg_barrier_lds();
}

// ---------------- persistent RNN kernel: 1 workgroup per batch ----------
// 512 threads = 8 waves.
template <bool PRE>
__global__ __launch_bounds__(512, 2)
void rnn_persistent(const float* __restrict__ x,
                    const float* __restrict__ h0,
                    const float* __restrict__ Winp,
                    const float* __restrict__ Wrec,
                    const float* __restrict__ brec,
                    const float* __restrict__ eta_ws,
                    float* __restrict__ out) {
  const int b   = blockIdx.x;
  const int tid = threadIdx.x;

  __shared__ float sh_h[NR];            // current hidden state
  __shared__ float sh_part[10 * NR];    // partials, k-major: [k*200 + row]
  __shared__ float sh_x[2][16];         // x_t double buffer
  __shared__ float sh_eta[2][NR];       // scaled noise double buffer

  const int  k_th = tid / 50;
  const int  r_th = tid % 50;
  const bool mac_active = (tid < 500);

  // --- stationary W_rec tile in registers ---
  float w[4][20];
  if (mac_active) {
#pragma unroll
    for (int j = 0; j < 4; ++j) {
      const float* wr = Wrec + (size_t)(4 * r_th + j) * NR + 20 * k_th;
#pragma unroll
      for (int q = 0; q < 5; ++q) {
        float4 v = *(const float4*)(wr + 4 * q);
        w[j][4 * q + 0] = v.x; w[j][4 * q + 1] = v.y;
        w[j][4 * q + 2] = v.z; w[j][4 * q + 3] = v.w;
      }
    }
  }

  // --- update-thread state ---
  float winp[NI];
  float brec_r = 0.0f;
  float h_reg  = 0.0f;
  float* obp   = nullptr;

  const float* xb   = x + (size_t)b * TSTEPS * NI;
  const float* etab = PRE ? (eta_ws + (size_t)b * NR) : nullptr;
  float* ob         = out + (size_t)b * TSTEPS * NR;

  if (tid < NR) {
#pragma unroll
    for (int i = 0; i < NI; ++i) winp[i] = Winp[tid * NI + i];
    brec_r = brec[tid];
    h_reg  = h0[(size_t)b * NR + tid];
    sh_h[tid] = h_reg;
    obp = ob + tid;
  }

  const uint32_t nb_b = (uint32_t)b * (uint32_t)NR;
  float  xnA = 0.0f, xnB = 0.0f;
  float4 enA = make_float4(0.f, 0.f, 0.f, 0.f);
  float4 enB = make_float4(0.f, 0.f, 0.f, 0.f);

  // --- bootstrap: eta(0)/x(0) -> buf0; (1),(2) -> regs ---
  if constexpr (PRE) {
    if (tid >= 256 && tid < 256 + NR / 4) {
      int j = tid - 256;
      *(float4*)(&sh_eta[0][4 * j]) = *(const float4*)(etab + 4 * j);
      enA = *(const float4*)(etab + (size_t)1 * ETA_STRIDE + 4 * j);  // eta(1)
      enB = *(const float4*)(etab + (size_t)2 * ETA_STRIDE + 4 * j);  // eta(2)
    }
  } else {
    if ((tid >= 256 && tid < 448) || (tid >= 200 && tid < 208)) {
      int n = (tid >= 256) ? (tid - 256) : (tid - 8);
      sh_eta[0][n] = NOISE_STD_F * jax_normal(nb_b + (uint32_t)n);  // t = 0
    }
  }
  if (tid >= 448 && tid < 448 + NI) {
    int j = tid - 448;
    sh_x[0][j] = xb[j];          // x(0)
    xnA = xb[NI + j];            // x(1), consumed at t=0
    xnB = xb[2 * NI + j];        // x(2), consumed at t=1
  }
  __syncthreads();

  const float* hp      = sh_h + 20 * k_th;            // 16B aligned
  float*       part_wp = sh_part + k_th * NR + 4 * r_th;

  // main loop: unroll x2, compile-time buffer indices; tail peeled
  for (int t = 0; t < TSTEPS - 2; t += 2) {
    rnn_step<0, true, PRE>(t,     tid, mac_active, w, winp, brec_r, h_reg, obp,
                           xnA, xnB, enA, enB, xb, etab, nb_b, hp, part_wp,
                           sh_h, sh_part, sh_x, sh_eta);
    rnn_step<1, true, PRE>(t + 1, tid, mac_active, w, winp, brec_r, h_reg, obp,
                           xnA, xnB, enA, enB, xb, etab, nb_b, hp, part_wp,
                           sh_h, sh_part, sh_x, sh_eta);
  }
  rnn_step<0, true,  PRE>(TSTEPS - 2, tid, mac_active, w, winp, brec_r, h_reg, obp,
                          xnA, xnB, enA, enB, xb, etab, nb_b, hp, part_wp,
                          sh_h, sh_part, sh_x, sh_eta);
  rnn_step<1, false, PRE>(TSTEPS - 1, tid, mac_active, w, winp, brec_r, h_reg, obp,
                          xnA, xnB, enA, enB, xb, etab, nb_b, hp, part_wp,
                          sh_h, sh_part, sh_x, sh_eta);
}

extern "C" void kernel_launch(void* const* d_in, const int* in_sizes, int n_in,
                              void* d_out, int out_size, void* d_ws, size_t ws_size,
                              hipStream_t stream) {
  const float* x    = (const float*)d_in[0];  // [256,1000,10]
  const float* h0   = (const float*)d_in[1];  // [256,200]
  const float* Winp = (const float*)d_in[2];  // [200,10]
  const float* Wrec = (const float*)d_in[3];  // [200,200]
  const float* brec = (const float*)d_in[4];  // [200]
  float* out = (float*)d_out;                 // [256,1000,200]
  (void)in_sizes; (void)n_in; (void)out_size;

  const size_t eta_bytes = ETA_FLOATS * sizeof(float);  // 204.8 MB
  if (d_ws != nullptr && ws_size >= eta_bytes) {
    // stage 1: dense noise map into workspace (stream-ordered before stage 2)
    noise_fill<<<dim3(4096), dim3(256), 0, stream>>>((float*)d_ws);
    // stage 2: persistent recurrence, eta streamed from workspace
    rnn_persistent<true><<<dim3(NB), dim3(512), 0, stream>>>(
        x, h0, Winp, Wrec, brec, (const float*)d_ws, out);
  } else {
    // fallback: in-kernel noise (identical to verified R1 kernel)
    rnn_persistent<false><<<dim3(NB), dim3(512), 0, stream>>>(
        x, h0, Winp, Wrec, brec, nullptr, out);
  }
}